// Round 12
// baseline (168.090 us; speedup 1.0000x reference)
//
#include <hip/hip_runtime.h>
#include <hip/hip_bf16.h>

#define B_ 2
#define S_ 2048
#define E_ 1024
#define H_ 16
#define D_ 64
// M = B_*S_ = 4096 rows

typedef __attribute__((ext_vector_type(8))) _Float16 half8;
typedef __attribute__((ext_vector_type(4))) _Float16 half4;
typedef __attribute__((ext_vector_type(4))) float floatx4;

__device__ inline void gload16(const _Float16* g, _Float16* l) {
    __builtin_amdgcn_global_load_lds(
        (const __attribute__((address_space(1))) void*)g,
        (__attribute__((address_space(3))) void*)l, 16, 0, 0);
}

// ---------------- fused preprocessing: x cvt + W_attn^T + W_proj^T ----------------
// (unchanged — verified)
__global__ __launch_bounds__(256) void k_prep(const float* __restrict__ x, _Float16* __restrict__ xh,
                                              const float* __restrict__ Wa, _Float16* __restrict__ Wat,
                                              const float* __restrict__ Wp, _Float16* __restrict__ Wpt) {
    __shared__ _Float16 tile[32][33];
    int bid = blockIdx.x, tid = threadIdx.x;
    if (bid < 2048) {
        int i = (bid * 256 + tid) * 8;
        float4 a = *(const float4*)(x + i);
        float4 b = *(const float4*)(x + i + 4);
        half8 o;
        o[0] = (_Float16)a.x; o[1] = (_Float16)a.y; o[2] = (_Float16)a.z; o[3] = (_Float16)a.w;
        o[4] = (_Float16)b.x; o[5] = (_Float16)b.y; o[6] = (_Float16)b.z; o[7] = (_Float16)b.w;
        *(half8*)(xh + i) = o;
        return;
    }
    const float* in;
    _Float16* out;
    int R, C, bx, by;
    if (bid < 5120) {
        int t = bid - 2048;
        in = Wa; out = Wat; R = E_; C = 3 * E_;
        bx = t % 96; by = t / 96;
    } else {
        int t = bid - 5120;
        in = Wp; out = Wpt; R = E_; C = E_;
        bx = t & 31; by = t >> 5;
    }
    int tx = tid & 31, ty = tid >> 5;
    int c0 = bx * 32, r0 = by * 32;
#pragma unroll
    for (int k = 0; k < 4; k++) {
        int r = ty + k * 8;
        tile[r][tx] = (_Float16)in[(size_t)(r0 + r) * C + c0 + tx];
    }
    __syncthreads();
#pragma unroll
    for (int k = 0; k < 4; k++) {
        int r = ty + k * 8;
        out[(size_t)(c0 + r) * R + r0 + tx] = tile[tx][r];
    }
}

// ---------------- QKV GEMM v5: 8-wave blocks (TLP fix) + BK=64 swizzle (r11) ----------------
// r11 post-mortem: BK=64 killed bank conflicts (3.2M -> 65K) but 64KB LDS at
// 256 threads halved residency to 8 waves/CU (occ 27->14) — the conflict win
// was eaten by TLP loss. v5 keeps the tile/swizzle and moves to 512 threads /
// 8 waves per block (the r4 attn lever): wave quadrant 32(m) x 64(n),
// acc[2][4], 2 blocks/CU -> 16 waves/CU = 4 waves/SIMD. Staging: each thread
// 4 gload16 (A,B x 2 row-shots). Epilogue: verified restage patterns at
// 32-row wave quadrants (Q/K full-line stores; V half-lines merged in L2
// across same-block waves within the same tight window).
__global__ __launch_bounds__(512, 4) void k_gemm0(const _Float16* __restrict__ A,
                                                  const _Float16* __restrict__ Bt,
                                                  const float* __restrict__ bias,
                                                  _Float16* __restrict__ outQ,
                                                  _Float16* __restrict__ outK,
                                                  _Float16* __restrict__ outV,
                                                  int M, int N, int K) {
    __shared__ __align__(16) _Float16 AsB[2 * 8192];
    __shared__ __align__(16) _Float16 BsB[2 * 8192];
    int tid = threadIdx.x;
    int lane = tid & 63, w = tid >> 6;  // w in [0,8)
    int wm = w & 3, wn = w >> 2;        // m-quarter (32 rows), n-half (64 cols)
    int l15 = lane & 15, quad = lane >> 4;
    // XCD rectangle remap, m-fastest within XCD for B-tile reuse (grid = 768)
    int xcd = blockIdx.x & 7, s = blockIdx.x >> 3;  // s in [0,96)
    int by = xcd * 4 + (s & 3);
    int bx = s >> 2;
    int m0 = by * 128, n0 = bx * 128;

    floatx4 acc[2][4];
    floatx4 zero = {0.f, 0.f, 0.f, 0.f};
#pragma unroll
    for (int i = 0; i < 2; i++)
#pragma unroll
        for (int j = 0; j < 4; j++) acc[i][j] = zero;

    // staging: swizzled layout LDS[row][c] = G[row][c ^ ((row&7)<<3)], rows of 64 halfs.
    // thread tid covers row = tid>>3 (shot0) and row+64 (shot1), chunk col = tid&7.
    int srow = tid >> 3;                                // 0..63
    int scol = (((tid & 7) ^ (srow & 7)) << 3);         // inverse-swizzled source col (halfs)
    const _Float16* aS = A + (size_t)(m0 + srow) * K + scol;
    const _Float16* bS = Bt + (size_t)(n0 + srow) * K + scol;
    const size_t rstep = (size_t)64 * K;                // shot1 = +64 rows ((row+64)&7 == row&7)

#define GSTAGE(ko_, buf_)                                \
    do {                                                 \
        _Float16* lA = AsB + (buf_) * 8192 + w * 512;    \
        _Float16* lB = BsB + (buf_) * 8192 + w * 512;    \
        gload16(aS + (ko_), lA);                         \
        gload16(aS + rstep + (ko_), lA + 4096);          \
        gload16(bS + (ko_), lB);                         \
        gload16(bS + rstep + (ko_), lB + 4096);          \
    } while (0)

    GSTAGE(0, 0);
    int cur = 0;
    int swz = (l15 & 7) << 3;  // read-side XOR (frag row&7 == l15&7)
    for (int k0 = 0; k0 < K; k0 += 64) {
        __syncthreads();  // drains buf[cur] staged last iter; prior reads done
        if (k0 + 64 < K) GSTAGE(k0 + 64, cur ^ 1);
        const _Float16* AC = AsB + cur * 8192;
        const _Float16* BC = BsB + cur * 8192;
#pragma unroll
        for (int kk = 0; kk < 2; kk++) {
            half8 af[2], bfr[4];
#pragma unroll
            for (int i = 0; i < 2; i++)
                af[i] = *(const half8*)&AC[(wm * 32 + i * 16 + l15) * 64 + ((kk * 32 + quad * 8) ^ swz)];
#pragma unroll
            for (int j = 0; j < 4; j++)
                bfr[j] = *(const half8*)&BC[(wn * 64 + j * 16 + l15) * 64 + ((kk * 32 + quad * 8) ^ swz)];
#pragma unroll
            for (int i = 0; i < 2; i++)
#pragma unroll
                for (int j = 0; j < 4; j++)
                    acc[i][j] = __builtin_amdgcn_mfma_f32_16x16x32_f16(af[i], bfr[j], acc[i][j], 0, 0, 0);
        }
        cur ^= 1;
    }
#undef GSTAGE

    // ---- coalesced epilogue: restage 32x64 quadrant in wave-private 4KB (dead AsB) ----
    __syncthreads();  // all waves done reading As/Bs
    _Float16* Ew = AsB + w * 2048;  // 4KB per wave (8 waves = 32KB = AsB)
    int gr0 = m0 + wm * 32;  // quadrant global row base (32-aligned)
    int gc0 = n0 + wn * 64;  // quadrant global col base (64-aligned)
    float bj[4];
#pragma unroll
    for (int j = 0; j < 4; j++) bj[j] = bias[gc0 + j * 16 + l15];

    int sect = gc0 >> 10;                  // 0=Q 1=K 2=V (uniform per quadrant)
    int hh = (gc0 & 1023) >> 6;            // head sub-block (uniform)
    int bb = gr0 >> 11, ss0 = gr0 & 2047;  // rows within one batch
    size_t hb = (size_t)(bb * H_ + hh);
    if (sect < 2) {
        // Q/K: LDS [ss 32][dd 64], dd XOR-swizzled by ss&7
#pragma unroll
        for (int i = 0; i < 2; i++)
#pragma unroll
            for (int j = 0; j < 4; j++)
#pragma unroll
                for (int r = 0; r < 4; r++) {
                    int rl = i * 16 + quad * 4 + r;
                    Ew[rl * 64 + ((j * 16 + l15) ^ ((rl & 7) << 3))] =
                        (_Float16)(acc[i][j][r] + bj[j]);
                }
        _Float16* dst = (sect == 0 ? outQ : outK) + (hb * S_ + ss0) * D_;
#pragma unroll
        for (int g = 0; g < 4; g++) {
            int rl = g * 8 + (lane >> 3);
            int c8 = (lane & 7) * 8;
            half8 v = *(const half8*)&Ew[rl * 64 + (c8 ^ ((rl & 7) << 3))];
            *(half8*)(dst + (size_t)rl * D_ + c8) = v;  // 1KB contiguous per wave-instr
        }
    } else {
        // V: transposed restage LDS [dd 64][ss 32], ss XOR-swizzled by dd&3 (b64 packed)
#pragma unroll
        for (int i = 0; i < 2; i++)
#pragma unroll
            for (int j = 0; j < 4; j++) {
                int dd = j * 16 + l15;
                half4 pk;
#pragma unroll
                for (int r = 0; r < 4; r++) pk[r] = (_Float16)(acc[i][j][r] + bj[j]);
                *(half4*)&Ew[dd * 32 + ((i * 16 + quad * 4) ^ ((dd & 3) << 3))] = pk;
            }
#pragma unroll
        for (int g = 0; g < 4; g++) {
            int dd = g * 16 + (lane >> 2);
            int s8 = (lane & 3) * 8;
            half8 v = *(const half8*)&Ew[dd * 32 + (s8 ^ ((dd & 3) << 3))];
            *(half8*)(outV + (hb * D_ + dd) * S_ + ss0 + s8) = v;  // 64B/row x 16 rows per instr
        }
    }
}

// ---------------- proj GEMM: BM=64 x BN=128 for 2 blocks/CU ----------------
// (unchanged from round 10 — verified)
__global__ __launch_bounds__(256) void k_gemm1(const _Float16* __restrict__ A,
                                               const _Float16* __restrict__ Bt,
                                               const float* __restrict__ bias,
                                               float* __restrict__ out,
                                               int M, int N, int K) {
    // halfs: As[2][2048] @0, Bs[2][4096] @4096  (24576 B)
    __shared__ __align__(16) _Float16 smem[12288];
    _Float16* AsB = smem;
    _Float16* BsB = smem + 4096;
    int tid = threadIdx.x;
    int lane = tid & 63, w = tid >> 6;
    int wm = w & 1, wn = w >> 1;
    int l15 = lane & 15, quad = lane >> 4;
    // XCD remap: grid 512, nbx = N/128 = 8; each XCD owns 8 m-panels (1MB, L2-resident)
    int nbx = N >> 7;
    int xcd = blockIdx.x & 7, s = blockIdx.x >> 3;
    int by = xcd * 8 + s / nbx;
    int bx = s % nbx;
    int m0 = by * 64, n0 = bx * 128;

    floatx4 acc[2][4];
    floatx4 zero = {0.f, 0.f, 0.f, 0.f};
#pragma unroll
    for (int i = 0; i < 2; i++)
#pragma unroll
        for (int j = 0; j < 4; j++) acc[i][j] = zero;

    // staging: A 64x32 halfs (1 chunk), B 128x32 (2 chunks); source col pre-XORed
    int srow = tid >> 2;                              // 0..63
    int scol = ((tid * 8) & 31) ^ ((srow & 3) << 3);  // (srow+64)&3 == srow&3
    const _Float16* aS = A + (size_t)(m0 + srow) * K + scol;
    const _Float16* bS0 = Bt + (size_t)(n0 + srow) * K + scol;
    const _Float16* bS1 = Bt + (size_t)(n0 + 64 + srow) * K + scol;

#define G1STAGE(ko_, buf_)                                         \
    do {                                                           \
        gload16(aS + (ko_), AsB + (buf_) * 2048 + w * 512);        \
        gload16(bS0 + (ko_), BsB + (buf_) * 4096 + w * 512);       \
        gload16(bS1 + (ko_), BsB + (buf_) * 4096 + 2048 + w * 512);\
    } while (0)

    G1STAGE(0, 0);
    int cur = 0;
    int sx = (l15 & 3) << 3;  // read-side XOR matching staged layout
    for (int k0 = 0; k0 < K; k0 += 32) {
        __syncthreads();  // drains buf[cur] staged last iter; prior reads done
        if (k0 + 32 < K) G1STAGE(k0 + 32, cur ^ 1);
        const _Float16* AC = AsB + cur * 2048;
        const _Float16* BC = BsB + cur * 4096;
        half8 af[2], bfr[4];
#pragma unroll
        for (int i = 0; i < 2; i++)
            af[i] = *(const half8*)&AC[(wm * 32 + i * 16 + l15) * 32 + ((quad * 8) ^ sx)];
#pragma unroll
        for (int j = 0; j < 4; j++)
            bfr[j] = *(const half8*)&BC[(wn * 64 + j * 16 + l15) * 32 + ((quad * 8) ^ sx)];
#pragma unroll
        for (int i = 0; i < 2; i++)
#pragma unroll
            for (int j = 0; j < 4; j++)
                acc[i][j] = __builtin_amdgcn_mfma_f32_16x16x32_f16(af[i], bfr[j], acc[i][j], 0, 0, 0);
        cur ^= 1;
    }
#undef G1STAGE

    // ---- 2-pass coalesced epilogue: wave-private 4KB f32 restage ----
    __syncthreads();
    float* Ef = (float*)smem + w * 1024;  // 4KB per wave (16KB of the 24KB total)
    int gr0 = m0 + wm * 32;
    int gc0 = n0 + wn * 64;
    float bj[4];
#pragma unroll
    for (int j = 0; j < 4; j++) bj[j] = bias[gc0 + j * 16 + l15];
#pragma unroll
    for (int i = 0; i < 2; i++) {
#pragma unroll
        for (int j = 0; j < 4; j++)
#pragma unroll
            for (int r = 0; r < 4; r++) {
                int rl = quad * 4 + r;
                Ef[rl * 64 + ((j * 16 + l15) ^ ((rl & 7) << 2))] = acc[i][j][r] + bj[j];
            }
        // wave-private region: in-wave ds ordering suffices, no barrier
#pragma unroll
        for (int g = 0; g < 4; g++) {
            int rl = g * 4 + (lane >> 4);
            int c4 = (lane & 15) * 4;
            float4 v = *(float4*)&Ef[rl * 64 + (c4 ^ ((rl & 7) << 2))];
            *(float4*)&out[(size_t)(gr0 + i * 16 + rl) * N + gc0 + c4] = v;
        }
    }
}

// ---------------- flash attention v6: 128-key intervals, half the barriers ----------------
// (exact round-8 kernel — verified best)
__global__ __launch_bounds__(512, 4)
void k_attn(const _Float16* __restrict__ Qh,
            const _Float16* __restrict__ Kh,
            const _Float16* __restrict__ Vt,
            _Float16* __restrict__ y) {
    // LDS halfs: Ks[2][8192] @0, Vs[2][8192] @16384, P[8][16*64] @32768 (81920 B)
    __shared__ __align__(16) _Float16 smem_h[40960];
    int tid = threadIdx.x;
    int lane = tid & 63, w = tid >> 6;  // w in [0,8)
    int l15 = lane & 15, quad = lane >> 4;
    _Float16* KsB = smem_h;
    _Float16* VsB = smem_h + 16384;
    _Float16* Pw = smem_h + 32768 + w * 1024;

    int bidx = blockIdx.x;  // [0,512)
    // bidx = [half(1)][qidx(3)][headSub(2)][xcd(3)]
    int bh = 4 * (bidx & 7) + ((bidx >> 3) & 3);  // 4 heads per XCD -> K+V 2MB L2-resident
    int qidx = (bidx >> 5) & 7;
    int qb = (bidx >> 8) ? qidx : (15 - qidx);  // (bidx, bidx+256) pair sums 15
    int b = bh >> 4, h = bh & 15;

    const size_t hbase = (size_t)bh * (S_ * D_);
    const _Float16* Qp = Qh + hbase;
    const _Float16* Kp = Kh + hbase;
    const _Float16* Vp = Vt + hbase;

    int q0w = qb * 128 + 16 * w;  // this wave's first query row

    // staging: thread fills tile-linear 16B at byte offset tid*16 within each 8KB sub-tile
    // swizzled layout: LDS[row*64 + (col ^ ((row&7)<<3))] = G[row][col]  (halfs)
    int r0 = tid >> 3;                             // rows 0..63
    int cbh = ((tid * 8) & 63) ^ ((r0 & 7) << 3);  // inverse-swizzled source col
    const _Float16* kS0 = Kp + (size_t)r0 * D_ + cbh;         // K rows 0-63 of interval
    const _Float16* kS1 = Kp + (size_t)(r0 + 64) * D_ + cbh;  // K rows 64-127
    const _Float16* vS0 = Vp + (size_t)r0 * S_ + cbh;         // V^T d-rows, keys 0-63
    const _Float16* vS1 = vS0 + 64;                           // keys 64-127

#define STAGE(kt_, buf_)                                                          \
    do {                                                                          \
        gload16(kS0 + (size_t)(kt_) * 8192, KsB + (buf_) * 8192 + w * 512);       \
        gload16(kS1 + (size_t)(kt_) * 8192, KsB + (buf_) * 8192 + 4096 + w * 512);\
        gload16(vS0 + (size_t)(kt_) * 128, VsB + (buf_) * 8192 + w * 512);        \
        gload16(vS1 + (size_t)(kt_) * 128, VsB + (buf_) * 8192 + 4096 + w * 512); \
    } while (0)

    // Q fragments, pre-scaled by 1/sqrt(D)=0.125 (exact in f16)
    half8 aq[2];
#pragma unroll
    for (int kk = 0; kk < 2; kk++) {
        half8 q = *(const half8*)(Qp + (size_t)(q0w + l15) * D_ + kk * 32 + quad * 8);
#pragma unroll
        for (int u = 0; u < 8; u++) q[u] *= (_Float16)0.125f;
        aq[kk] = q;
    }

    floatx4 zero = {0.f, 0.f, 0.f, 0.f};
    floatx4 o[4];
#pragma unroll
    for (int f = 0; f < 4; f++) o[f] = zero;
    float l_run = 0.f;

    STAGE(0, 0);
    int cur = 0;
    int swz = (l15 & 7) << 3;  // XOR for K/V reads and P write/read, in halfs
    for (int kt = 0; kt <= qb; kt++) {
        __syncthreads();  // buf[cur] staged (vmcnt drain); prior reads of buf[cur^1] done
        if (kt < qb) STAGE(kt + 1, cur ^ 1);
        bool diag = (kt == qb);
#pragma unroll
        for (int t = 0; t < 2; t++) {
            if (diag && t == 1 && w < 4) break;  // upper half fully masked for waves 0-3
            int k64 = kt * 128 + t * 64;
            const _Float16* KC = KsB + cur * 8192 + t * 4096;
            const _Float16* VC = VsB + cur * 8192 + t * 4096;
            // QK^T (swapped operands: D[key][query])
            floatx4 sa[4];
            __builtin_amdgcn_s_setprio(1);
#pragma unroll
            for (int jj = 0; jj < 4; jj++) {
                int row = jj * 16 + l15;
                half8 k0 = *(const half8*)&KC[row * 64 + ((quad * 8) ^ swz)];
                half8 k1 = *(const half8*)&KC[row * 64 + ((32 + quad * 8) ^ swz)];
                floatx4 a = zero;
                a = __builtin_amdgcn_mfma_f32_16x16x32_f16(k0, aq[0], a, 0, 0, 0);
                a = __builtin_amdgcn_mfma_f32_16x16x32_f16(k1, aq[1], a, 0, 0, 0);
                sa[jj] = a;
            }
            __builtin_amdgcn_s_setprio(0);
            float ssum = 0.f;
#pragma unroll
            for (int jj = 0; jj < 4; jj++) {
                half4 pk;
#pragma unroll
                for (int r = 0; r < 4; r++) {
                    float v = __expf(sa[jj][r]);
                    if (diag) {
                        int key = k64 + jj * 16 + quad * 4 + r;
                        int query = q0w + l15;
                        if (key > query) v = 0.f;
                    }
                    ssum += v;
                    pk[r] = (_Float16)v;
                }
                // P^T in C-layout -> store as P[q][key], XOR-swizzled (stride 64)
                *(half4*)&Pw[l15 * 64 + ((jj * 16 + quad * 4) ^ swz)] = pk;
            }
            ssum += __shfl_xor(ssum, 16);
            ssum += __shfl_xor(ssum, 32);
            l_run += ssum;
            // O += P V: A-frag of P from LDS (same XOR), B-frag of V^T from LDS
            __builtin_amdgcn_s_setprio(1);
#pragma unroll
            for (int kk = 0; kk < 2; kk++) {
                half8 ap = *(const half8*)&Pw[l15 * 64 + ((kk * 32 + quad * 8) ^ swz)];
#pragma unroll
                for (int f = 0; f < 4; f++) {
                    int row = f * 16 + l15;
                    half8 bv = *(const half8*)&VC[row * 64 + ((kk * 32 + quad * 8) ^ swz)];
                    o[f] = __builtin_amdgcn_mfma_f32_16x16x32_f16(ap, bv, o[f], 0, 0, 0);
                }
            }
            __builtin_amdgcn_s_setprio(0);
        }
        cur ^= 1;
    }
#undef STAGE

    // epilogue: query = q0w+quad*4+r (D-layout row), d = f*16+l15 (col)
    float linv[4];
#pragma unroll
    for (int r = 0; r < 4; r++) linv[r] = 1.0f / __shfl(l_run, quad * 4 + r);
#pragma unroll
    for (int f = 0; f < 4; f++)
#pragma unroll
        for (int r = 0; r < 4; r++) {
            int row = q0w + quad * 4 + r;
            y[((size_t)(b * S_ + row)) * E_ + h * D_ + f * 16 + l15] =
                (_Float16)(o[f][r] * linv[r]);
        }
}

extern "C" void kernel_launch(void* const* d_in, const int* in_sizes, int n_in,
                              void* d_out, int out_size, void* d_ws, size_t ws_size,
                              hipStream_t stream) {
    const float* x      = (const float*)d_in[0];
    const float* W_attn = (const float*)d_in[1];
    const float* b_attn = (const float*)d_in[2];
    const float* W_proj = (const float*)d_in[3];
    const float* b_proj = (const float*)d_in[4];
    float* out = (float*)d_out;

    const int M = B_ * S_;  // 4096
    char* ws = (char*)d_ws;
    _Float16* xh  = (_Float16*)ws; ws += (size_t)M * E_ * 2;       // 8 MB
    _Float16* Wat = (_Float16*)ws; ws += (size_t)3 * E_ * E_ * 2;  // 6 MB
    _Float16* Wpt = (_Float16*)ws; ws += (size_t)E_ * E_ * 2;      // 2 MB
    _Float16* Qh  = (_Float16*)ws; ws += (size_t)M * E_ * 2;       // 8 MB
    _Float16* Kh  = (_Float16*)ws; ws += (size_t)M * E_ * 2;       // 8 MB
    _Float16* Vt  = (_Float16*)ws; ws += (size_t)M * E_ * 2;       // 8 MB
    _Float16* yh  = xh;  // xh dead after QKV GEMM

    k_prep<<<6144, 256, 0, stream>>>(x, xh, W_attn, Wat, W_proj, Wpt);
    k_gemm0<<<768, 512, 0, stream>>>(xh, Wat, b_attn, Qh, Kh, Vt, M, 3 * E_, E_);
    k_attn<<<512, 512, 0, stream>>>(Qh, Kh, Vt, yh);
    k_gemm1<<<512, 256, 0, stream>>>(yh, Wpt, b_proj, out, M, E_, E_);
}

// Round 14
// 164.252 us; speedup vs baseline: 1.0234x; 1.0234x over previous
//
#include <hip/hip_runtime.h>
#include <hip/hip_bf16.h>

#define B_ 2
#define S_ 2048
#define E_ 1024
#define H_ 16
#define D_ 64
// M = B_*S_ = 4096 rows

typedef __attribute__((ext_vector_type(8))) _Float16 half8;
typedef __attribute__((ext_vector_type(4))) _Float16 half4;
typedef __attribute__((ext_vector_type(4))) float floatx4;

__device__ inline void gload16(const _Float16* g, _Float16* l) {
    __builtin_amdgcn_global_load_lds(
        (const __attribute__((address_space(1))) void*)g,
        (__attribute__((address_space(3))) void*)l, 16, 0, 0);
}

// ---------------- fused preprocessing: x cvt + W_attn^T + W_proj^T ----------------
// grid partition (block-uniform branch): [0,2048) cvt x (f32->f16, 2048 elems/blk)
//   [2048,5120) transpose W_attn (96x32 tiles)  [5120,6144) transpose W_proj (32x32)
__global__ __launch_bounds__(256) void k_prep(const float* __restrict__ x, _Float16* __restrict__ xh,
                                              const float* __restrict__ Wa, _Float16* __restrict__ Wat,
                                              const float* __restrict__ Wp, _Float16* __restrict__ Wpt) {
    __shared__ _Float16 tile[32][33];
    int bid = blockIdx.x, tid = threadIdx.x;
    if (bid < 2048) {
        int i = (bid * 256 + tid) * 8;
        float4 a = *(const float4*)(x + i);
        float4 b = *(const float4*)(x + i + 4);
        half8 o;
        o[0] = (_Float16)a.x; o[1] = (_Float16)a.y; o[2] = (_Float16)a.z; o[3] = (_Float16)a.w;
        o[4] = (_Float16)b.x; o[5] = (_Float16)b.y; o[6] = (_Float16)b.z; o[7] = (_Float16)b.w;
        *(half8*)(xh + i) = o;
        return;
    }
    const float* in;
    _Float16* out;
    int R, C, bx, by;
    if (bid < 5120) {
        int t = bid - 2048;
        in = Wa; out = Wat; R = E_; C = 3 * E_;
        bx = t % 96; by = t / 96;
    } else {
        int t = bid - 5120;
        in = Wp; out = Wpt; R = E_; C = E_;
        bx = t & 31; by = t >> 5;
    }
    int tx = tid & 31, ty = tid >> 5;
    int c0 = bx * 32, r0 = by * 32;
#pragma unroll
    for (int k = 0; k < 4; k++) {
        int r = ty + k * 8;
        tile[r][tx] = (_Float16)in[(size_t)(r0 + r) * C + c0 + tx];
    }
    __syncthreads();
#pragma unroll
    for (int k = 0; k < 4; k++) {
        int r = ty + k * 8;
        out[(size_t)(c0 + r) * R + r0 + tx] = tile[tx][r];
    }
}

// ---------------- f16 MFMA GEMM v3 (MODE 0 only): dbuf loop + coalesced LDS-restage epilogue ----------------
// (unchanged from round 6 — verified)
template <int MODE>
__global__ __launch_bounds__(256) void k_gemm(const _Float16* __restrict__ A,
                                              const _Float16* __restrict__ Bt,
                                              const float* __restrict__ bias,
                                              void* __restrict__ out0,
                                              _Float16* __restrict__ out1,
                                              _Float16* __restrict__ out2,
                                              int M, int N, int K) {
    __shared__ __align__(16) _Float16 AsB[2 * 4096];
    __shared__ __align__(16) _Float16 BsB[2 * 4096];
    int tid = threadIdx.x;
    int lane = tid & 63, w = tid >> 6;
    int wm = w >> 1, wn = w & 1;
    int l15 = lane & 15, quad = lane >> 4;
    // XCD rectangle remap (grid = nbx*32, %8==0)
    int nbx = N >> 7;
    int xcd = blockIdx.x & 7, s = blockIdx.x >> 3;
    int by = xcd * 4 + s / nbx;
    int bx = s % nbx;
    int m0 = by * 128, n0 = bx * 128;

    floatx4 acc[4][4];
    floatx4 zero = {0.f, 0.f, 0.f, 0.f};
#pragma unroll
    for (int i = 0; i < 4; i++)
#pragma unroll
        for (int j = 0; j < 4; j++) acc[i][j] = zero;

    // staging source precompute (LDS-linear dest; source col pre-XORed)
    int srow = tid >> 2;                                   // 0..63
    int scol = ((tid * 8) & 31) ^ ((srow & 3) << 3);       // (srow+64)&3 == srow&3
    const _Float16* aS0 = A + (size_t)(m0 + srow) * K + scol;
    const _Float16* aS1 = A + (size_t)(m0 + 64 + srow) * K + scol;
    const _Float16* bS0 = Bt + (size_t)(n0 + srow) * K + scol;
    const _Float16* bS1 = Bt + (size_t)(n0 + 64 + srow) * K + scol;

#define GSTAGE(ko_, buf_)                                          \
    do {                                                           \
        gload16(aS0 + (ko_), AsB + (buf_) * 4096 + w * 512);       \
        gload16(aS1 + (ko_), AsB + (buf_) * 4096 + 2048 + w * 512);\
        gload16(bS0 + (ko_), BsB + (buf_) * 4096 + w * 512);       \
        gload16(bS1 + (ko_), BsB + (buf_) * 4096 + 2048 + w * 512);\
    } while (0)

    GSTAGE(0, 0);
    int cur = 0;
    int sx = (l15 & 3) << 3;  // read-side XOR matching staged layout
    for (int k0 = 0; k0 < K; k0 += 32) {
        __syncthreads();  // drains buf[cur] staged last iter; prior reads done
        if (k0 + 32 < K) GSTAGE(k0 + 32, cur ^ 1);
        const _Float16* AC = AsB + cur * 4096;
        const _Float16* BC = BsB + cur * 4096;
        half8 af[4], bfr[4];
#pragma unroll
        for (int i = 0; i < 4; i++)
            af[i] = *(const half8*)&AC[(wm * 64 + i * 16 + l15) * 32 + ((quad * 8) ^ sx)];
#pragma unroll
        for (int j = 0; j < 4; j++)
            bfr[j] = *(const half8*)&BC[(wn * 64 + j * 16 + l15) * 32 + ((quad * 8) ^ sx)];
#pragma unroll
        for (int i = 0; i < 4; i++)
#pragma unroll
            for (int j = 0; j < 4; j++)
                acc[i][j] = __builtin_amdgcn_mfma_f32_16x16x32_f16(af[i], bfr[j], acc[i][j], 0, 0, 0);
        cur ^= 1;
    }
#undef GSTAGE

    // ---- coalesced epilogue: restage quadrant in wave-private 8KB of dead staging LDS ----
    __syncthreads();  // all waves done reading As/Bs
    _Float16* Ew = (w < 2 ? AsB : BsB) + (w & 1) * 4096;
    int gr0 = m0 + wm * 64;  // quadrant global row base
    int gc0 = n0 + wn * 64;  // quadrant global col base (64-aligned)
    float bj[4];
#pragma unroll
    for (int j = 0; j < 4; j++) bj[j] = bias[gc0 + j * 16 + l15];

    if (MODE == 1) {
        float* Ef = (float*)Ew;  // [32 rows][64 cols] f32, XOR-swizzled cols
        float* outf = (float*)out0;
#pragma unroll
        for (int ip = 0; ip < 2; ip++) {
#pragma unroll
            for (int ii = 0; ii < 2; ii++) {
                int i = ip * 2 + ii;
#pragma unroll
                for (int j = 0; j < 4; j++)
#pragma unroll
                    for (int r = 0; r < 4; r++) {
                        int rl = ii * 16 + quad * 4 + r;
                        Ef[rl * 64 + ((j * 16 + l15) ^ ((rl & 7) << 2))] = acc[i][j][r] + bj[j];
                    }
            }
            // wave-private region: in-wave ds ordering suffices, no barrier
#pragma unroll
            for (int g = 0; g < 8; g++) {
                int rl = g * 4 + (lane >> 4);
                int c4 = (lane & 15) * 4;
                float4 v = *(float4*)&Ef[rl * 64 + (c4 ^ ((rl & 7) << 2))];
                *(float4*)&outf[(size_t)(gr0 + ip * 32 + rl) * N + gc0 + c4] = v;
            }
        }
    } else {
        int sect = gc0 >> 10;
        int hh = (gc0 & 1023) >> 6;            // quadrant = exactly one head sub-block
        int bb = gr0 >> 11, ss0 = gr0 & 2047;  // quadrant rows within one batch
        size_t hb = (size_t)(bb * H_ + hh);
        if (sect < 2) {
            // Q/K: LDS [ss 64][dd 64], dd XOR-swizzled by ss&7
#pragma unroll
            for (int i = 0; i < 4; i++)
#pragma unroll
                for (int j = 0; j < 4; j++)
#pragma unroll
                    for (int r = 0; r < 4; r++) {
                        int rl = i * 16 + quad * 4 + r;
                        Ew[rl * 64 + ((j * 16 + l15) ^ ((rl & 7) << 3))] =
                            (_Float16)(acc[i][j][r] + bj[j]);
                    }
            _Float16* dst = (sect == 0 ? (_Float16*)out0 : out1) + (hb * S_ + ss0) * D_;
#pragma unroll
            for (int g = 0; g < 8; g++) {
                int rl = g * 8 + (lane >> 3);
                int c8 = (lane & 7) * 8;
                half8 v = *(const half8*)&Ew[rl * 64 + (c8 ^ ((rl & 7) << 3))];
                *(half8*)(dst + (size_t)rl * D_ + c8) = v;  // 1KB contiguous per wave-instr
            }
        } else {
            // V: transposed restage LDS [dd 64][ss 64], ss XOR-swizzled by dd&7 (b64 packed)
#pragma unroll
            for (int i = 0; i < 4; i++)
#pragma unroll
                for (int j = 0; j < 4; j++) {
                    int dd = j * 16 + l15;
                    half4 pk;
#pragma unroll
                    for (int r = 0; r < 4; r++) pk[r] = (_Float16)(acc[i][j][r] + bj[j]);
                    *(half4*)&Ew[dd * 64 + ((i * 16 + quad * 4) ^ ((dd & 7) << 3))] = pk;
                }
#pragma unroll
            for (int g = 0; g < 8; g++) {
                int dd = g * 8 + (lane >> 3);
                int s8 = (lane & 7) * 8;
                half8 v = *(const half8*)&Ew[dd * 64 + (s8 ^ ((dd & 7) << 3))];
                *(half8*)(out2 + (hb * D_ + dd) * S_ + ss0 + s8) = v;  // 8 full lines per instr
            }
        }
    }
}

// ---------------- proj GEMM: BM=64 x BN=128 for 2 blocks/CU ----------------
// (unchanged from round 10 — verified)
__global__ __launch_bounds__(256) void k_gemm1(const _Float16* __restrict__ A,
                                               const _Float16* __restrict__ Bt,
                                               const float* __restrict__ bias,
                                               float* __restrict__ out,
                                               int M, int N, int K) {
    // halfs: As[2][2048] @0, Bs[2][4096] @4096  (24576 B)
    __shared__ __align__(16) _Float16 smem[12288];
    _Float16* AsB = smem;
    _Float16* BsB = smem + 4096;
    int tid = threadIdx.x;
    int lane = tid & 63, w = tid >> 6;
    int wm = w & 1, wn = w >> 1;
    int l15 = lane & 15, quad = lane >> 4;
    // XCD remap: grid 512, nbx = N/128 = 8; each XCD owns 8 m-panels (1MB, L2-resident)
    int nbx = N >> 7;
    int xcd = blockIdx.x & 7, s = blockIdx.x >> 3;
    int by = xcd * 8 + s / nbx;
    int bx = s % nbx;
    int m0 = by * 64, n0 = bx * 128;

    floatx4 acc[2][4];
    floatx4 zero = {0.f, 0.f, 0.f, 0.f};
#pragma unroll
    for (int i = 0; i < 2; i++)
#pragma unroll
        for (int j = 0; j < 4; j++) acc[i][j] = zero;

    // staging: A 64x32 halfs (1 chunk), B 128x32 (2 chunks); source col pre-XORed
    int srow = tid >> 2;                              // 0..63
    int scol = ((tid * 8) & 31) ^ ((srow & 3) << 3);  // (srow+64)&3 == srow&3
    const _Float16* aS = A + (size_t)(m0 + srow) * K + scol;
    const _Float16* bS0 = Bt + (size_t)(n0 + srow) * K + scol;
    const _Float16* bS1 = Bt + (size_t)(n0 + 64 + srow) * K + scol;

#define G1STAGE(ko_, buf_)                                         \
    do {                                                           \
        gload16(aS + (ko_), AsB + (buf_) * 2048 + w * 512);        \
        gload16(bS0 + (ko_), BsB + (buf_) * 4096 + w * 512);       \
        gload16(bS1 + (ko_), BsB + (buf_) * 4096 + 2048 + w * 512);\
    } while (0)

    G1STAGE(0, 0);
    int cur = 0;
    int sx = (l15 & 3) << 3;  // read-side XOR matching staged layout
    for (int k0 = 0; k0 < K; k0 += 32) {
        __syncthreads();  // drains buf[cur] staged last iter; prior reads done
        if (k0 + 32 < K) G1STAGE(k0 + 32, cur ^ 1);
        const _Float16* AC = AsB + cur * 2048;
        const _Float16* BC = BsB + cur * 4096;
        half8 af[2], bfr[4];
#pragma unroll
        for (int i = 0; i < 2; i++)
            af[i] = *(const half8*)&AC[(wm * 32 + i * 16 + l15) * 32 + ((quad * 8) ^ sx)];
#pragma unroll
        for (int j = 0; j < 4; j++)
            bfr[j] = *(const half8*)&BC[(wn * 64 + j * 16 + l15) * 32 + ((quad * 8) ^ sx)];
#pragma unroll
        for (int i = 0; i < 2; i++)
#pragma unroll
            for (int j = 0; j < 4; j++)
                acc[i][j] = __builtin_amdgcn_mfma_f32_16x16x32_f16(af[i], bfr[j], acc[i][j], 0, 0, 0);
        cur ^= 1;
    }
#undef G1STAGE

    // ---- 2-pass coalesced epilogue: wave-private 4KB f32 restage ----
    __syncthreads();
    float* Ef = (float*)smem + w * 1024;  // 4KB per wave (16KB of the 24KB total)
    int gr0 = m0 + wm * 32;
    int gc0 = n0 + wn * 64;
    float bj[4];
#pragma unroll
    for (int j = 0; j < 4; j++) bj[j] = bias[gc0 + j * 16 + l15];
#pragma unroll
    for (int i = 0; i < 2; i++) {
#pragma unroll
        for (int j = 0; j < 4; j++)
#pragma unroll
            for (int r = 0; r < 4; r++) {
                int rl = quad * 4 + r;
                Ef[rl * 64 + ((j * 16 + l15) ^ ((rl & 7) << 2))] = acc[i][j][r] + bj[j];
            }
        // wave-private region: in-wave ds ordering suffices, no barrier
#pragma unroll
        for (int g = 0; g < 4; g++) {
            int rl = g * 4 + (lane >> 4);
            int c4 = (lane & 15) * 4;
            float4 v = *(float4*)&Ef[rl * 64 + (c4 ^ ((rl & 7) << 2))];
            *(float4*)&out[(size_t)(gr0 + i * 16 + rl) * N + gc0 + c4] = v;
        }
    }
}

// ---------------- flash attention v6: 128-key intervals, half the barriers ----------------
// (exact round-8 kernel — verified best)
__global__ __launch_bounds__(512, 4)
void k_attn(const _Float16* __restrict__ Qh,
            const _Float16* __restrict__ Kh,
            const _Float16* __restrict__ Vt,
            _Float16* __restrict__ y) {
    // LDS halfs: Ks[2][8192] @0, Vs[2][8192] @16384, P[8][16*64] @32768 (81920 B)
    __shared__ __align__(16) _Float16 smem_h[40960];
    int tid = threadIdx.x;
    int lane = tid & 63, w = tid >> 6;  // w in [0,8)
    int l15 = lane & 15, quad = lane >> 4;
    _Float16* KsB = smem_h;
    _Float16* VsB = smem_h + 16384;
    _Float16* Pw = smem_h + 32768 + w * 1024;

    int bidx = blockIdx.x;  // [0,512)
    // bidx = [half(1)][qidx(3)][headSub(2)][xcd(3)]
    int bh = 4 * (bidx & 7) + ((bidx >> 3) & 3);  // 4 heads per XCD -> K+V 2MB L2-resident
    int qidx = (bidx >> 5) & 7;
    int qb = (bidx >> 8) ? qidx : (15 - qidx);  // (bidx, bidx+256) pair sums 15
    int b = bh >> 4, h = bh & 15;

    const size_t hbase = (size_t)bh * (S_ * D_);
    const _Float16* Qp = Qh + hbase;
    const _Float16* Kp = Kh + hbase;
    const _Float16* Vp = Vt + hbase;

    int q0w = qb * 128 + 16 * w;  // this wave's first query row

    // staging: thread fills tile-linear 16B at byte offset tid*16 within each 8KB sub-tile
    // swizzled layout: LDS[row*64 + (col ^ ((row&7)<<3))] = G[row][col]  (halfs)
    int r0 = tid >> 3;                             // rows 0..63
    int cbh = ((tid * 8) & 63) ^ ((r0 & 7) << 3);  // inverse-swizzled source col
    const _Float16* kS0 = Kp + (size_t)r0 * D_ + cbh;         // K rows 0-63 of interval
    const _Float16* kS1 = Kp + (size_t)(r0 + 64) * D_ + cbh;  // K rows 64-127
    const _Float16* vS0 = Vp + (size_t)r0 * S_ + cbh;         // V^T d-rows, keys 0-63
    const _Float16* vS1 = vS0 + 64;                           // keys 64-127

#define STAGE(kt_, buf_)                                                          \
    do {                                                                          \
        gload16(kS0 + (size_t)(kt_) * 8192, KsB + (buf_) * 8192 + w * 512);       \
        gload16(kS1 + (size_t)(kt_) * 8192, KsB + (buf_) * 8192 + 4096 + w * 512);\
        gload16(vS0 + (size_t)(kt_) * 128, VsB + (buf_) * 8192 + w * 512);        \
        gload16(vS1 + (size_t)(kt_) * 128, VsB + (buf_) * 8192 + 4096 + w * 512); \
    } while (0)

    // Q fragments, pre-scaled by 1/sqrt(D)=0.125 (exact in f16)
    half8 aq[2];
#pragma unroll
    for (int kk = 0; kk < 2; kk++) {
        half8 q = *(const half8*)(Qp + (size_t)(q0w + l15) * D_ + kk * 32 + quad * 8);
#pragma unroll
        for (int u = 0; u < 8; u++) q[u] *= (_Float16)0.125f;
        aq[kk] = q;
    }

    floatx4 zero = {0.f, 0.f, 0.f, 0.f};
    floatx4 o[4];
#pragma unroll
    for (int f = 0; f < 4; f++) o[f] = zero;
    float l_run = 0.f;

    STAGE(0, 0);
    int cur = 0;
    int swz = (l15 & 7) << 3;  // XOR for K/V reads and P write/read, in halfs
    for (int kt = 0; kt <= qb; kt++) {
        __syncthreads();  // buf[cur] staged (vmcnt drain); prior reads of buf[cur^1] done
        if (kt < qb) STAGE(kt + 1, cur ^ 1);
        bool diag = (kt == qb);
#pragma unroll
        for (int t = 0; t < 2; t++) {
            if (diag && t == 1 && w < 4) break;  // upper half fully masked for waves 0-3
            int k64 = kt * 128 + t * 64;
            const _Float16* KC = KsB + cur * 8192 + t * 4096;
            const _Float16* VC = VsB + cur * 8192 + t * 4096;
            // QK^T (swapped operands: D[key][query])
            floatx4 sa[4];
            __builtin_amdgcn_s_setprio(1);
#pragma unroll
            for (int jj = 0; jj < 4; jj++) {
                int row = jj * 16 + l15;
                half8 k0 = *(const half8*)&KC[row * 64 + ((quad * 8) ^ swz)];
                half8 k1 = *(const half8*)&KC[row * 64 + ((32 + quad * 8) ^ swz)];
                floatx4 a = zero;
                a = __builtin_amdgcn_mfma_f32_16x16x32_f16(k0, aq[0], a, 0, 0, 0);
                a = __builtin_amdgcn_mfma_f32_16x16x32_f16(k1, aq[1], a, 0, 0, 0);
                sa[jj] = a;
            }
            __builtin_amdgcn_s_setprio(0);
            float ssum = 0.f;
#pragma unroll
            for (int jj = 0; jj < 4; jj++) {
                half4 pk;
#pragma unroll
                for (int r = 0; r < 4; r++) {
                    float v = __expf(sa[jj][r]);
                    if (diag) {
                        int key = k64 + jj * 16 + quad * 4 + r;
                        int query = q0w + l15;
                        if (key > query) v = 0.f;
                    }
                    ssum += v;
                    pk[r] = (_Float16)v;
                }
                // P^T in C-layout -> store as P[q][key], XOR-swizzled (stride 64)
                *(half4*)&Pw[l15 * 64 + ((jj * 16 + quad * 4) ^ swz)] = pk;
            }
            ssum += __shfl_xor(ssum, 16);
            ssum += __shfl_xor(ssum, 32);
            l_run += ssum;
            // O += P V: A-frag of P from LDS (same XOR), B-frag of V^T from LDS
            __builtin_amdgcn_s_setprio(1);
#pragma unroll
            for (int kk = 0; kk < 2; kk++) {
                half8 ap = *(const half8*)&Pw[l15 * 64 + ((kk * 32 + quad * 8) ^ swz)];
#pragma unroll
                for (int f = 0; f < 4; f++) {
                    int row = f * 16 + l15;
                    half8 bv = *(const half8*)&VC[row * 64 + ((kk * 32 + quad * 8) ^ swz)];
                    o[f] = __builtin_amdgcn_mfma_f32_16x16x32_f16(ap, bv, o[f], 0, 0, 0);
                }
            }
            __builtin_amdgcn_s_setprio(0);
        }
        cur ^= 1;
    }
#undef STAGE

    // epilogue: query = q0w+quad*4+r (D-layout row), d = f*16+l15 (col)
    float linv[4];
#pragma unroll
    for (int r = 0; r < 4; r++) linv[r] = 1.0f / __shfl(l_run, quad * 4 + r);
#pragma unroll
    for (int f = 0; f < 4; f++)
#pragma unroll
        for (int r = 0; r < 4; r++) {
            int row = q0w + quad * 4 + r;
            y[((size_t)(b * S_ + row)) * E_ + h * D_ + f * 16 + l15] =
                (_Float16)(o[f][r] * linv[r]);
        }
}

extern "C" void kernel_launch(void* const* d_in, const int* in_sizes, int n_in,
                              void* d_out, int out_size, void* d_ws, size_t ws_size,
                              hipStream_t stream) {
    const float* x      = (const float*)d_in[0];
    const float* W_attn = (const float*)d_in[1];
    const float* b_attn = (const float*)d_in[2];
    const float* W_proj = (const float*)d_in[3];
    const float* b_proj = (const float*)d_in[4];
    float* out = (float*)d_out;

    const int M = B_ * S_;  // 4096
    char* ws = (char*)d_ws;
    _Float16* xh  = (_Float16*)ws; ws += (size_t)M * E_ * 2;       // 8 MB
    _Float16* Wat = (_Float16*)ws; ws += (size_t)3 * E_ * E_ * 2;  // 6 MB
    _Float16* Wpt = (_Float16*)ws; ws += (size_t)E_ * E_ * 2;      // 2 MB
    _Float16* Qh  = (_Float16*)ws; ws += (size_t)M * E_ * 2;       // 8 MB
    _Float16* Kh  = (_Float16*)ws; ws += (size_t)M * E_ * 2;       // 8 MB
    _Float16* Vt  = (_Float16*)ws; ws += (size_t)M * E_ * 2;       // 8 MB
    _Float16* yh  = xh;  // xh dead after QKV GEMM

    k_prep<<<6144, 256, 0, stream>>>(x, xh, W_attn, Wat, W_proj, Wpt);
    k_gemm<0><<<768, 256, 0, stream>>>(xh, Wat, b_attn, Qh, Kh, Vt, M, 3 * E_, E_);
    k_attn<<<512, 512, 0, stream>>>(Qh, Kh, Vt, yh);
    k_gemm1<<<512, 256, 0, stream>>>(yh, Wpt, b_proj, out, M, E_, E_);
}